// Round 1
// baseline (1287.618 us; speedup 1.0000x reference)
//
#include <hip/hip_runtime.h>
#include <cstdint>
#include <cstddef>

// ---------- types ----------
typedef __bf16 bf16;
typedef __bf16 bf16x8 __attribute__((ext_vector_type(8)));
typedef float  f32x4  __attribute__((ext_vector_type(4)));
typedef unsigned short u16x4v __attribute__((ext_vector_type(4)));

#define MFMA16(a, b, c) __builtin_amdgcn_mfma_f32_16x16x32_bf16((a), (b), (c), 0, 0, 0)

// async global->LDS, 16B per lane. LDS dst is wave-uniform base + lane*16 (HW adds lane part).
__device__ __forceinline__ void glds16(const bf16* g, bf16* l) {
    __builtin_amdgcn_global_load_lds(
        (__attribute__((address_space(1))) void*)(g),
        (__attribute__((address_space(3))) void*)(l), 16, 0, 0);
}

// DPP row (16-lane) rotate helpers for softmax reductions (no LDS traffic).
template <int N>
__device__ __forceinline__ float dpp_ror(float x) {
    int r = __builtin_amdgcn_update_dpp(0, __builtin_bit_cast(int, x), 0x120 | N, 0xF, 0xF, true);
    return __builtin_bit_cast(float, r);
}
__device__ __forceinline__ float rowmax16(float x) {
    x = fmaxf(x, dpp_ror<1>(x));
    x = fmaxf(x, dpp_ror<2>(x));
    x = fmaxf(x, dpp_ror<4>(x));
    x = fmaxf(x, dpp_ror<8>(x));
    return x;
}
__device__ __forceinline__ float rowsum16(float x) {
    x = x + dpp_ror<1>(x);
    x = x + dpp_ror<2>(x);
    x = x + dpp_ror<4>(x);
    x = x + dpp_ror<8>(x);
    return x;
}

// ---------- conversion kernels ----------
__global__ __launch_bounds__(256) void cvt_bf16_k(const float* __restrict__ in,
                                                  bf16* __restrict__ out, long long n) {
    long long i = ((long long)blockIdx.x * 256 + threadIdx.x) * 8;
    if (i >= n) return;
    const float4* p = (const float4*)(in + i);
    float4 a = p[0], b = p[1];
    bf16x8 o;
    o[0] = (bf16)a.x; o[1] = (bf16)a.y; o[2] = (bf16)a.z; o[3] = (bf16)a.w;
    o[4] = (bf16)b.x; o[5] = (bf16)b.y; o[6] = (bf16)b.z; o[7] = (bf16)b.w;
    *(bf16x8*)(out + i) = o;
}

// past_k [4][8][1024][128] f32 -> Kcache [4][8][2048][128] bf16 (first 1024 rows)
__global__ __launch_bounds__(256) void cvt_pastk_k(const float* __restrict__ in,
                                                   bf16* __restrict__ Kc) {
    long long e = ((long long)blockIdx.x * 256 + threadIdx.x) * 8;
    long long bh = e >> 17;          // / (1024*128)
    long long rem = e & 131071;
    const float4* p = (const float4*)(in + e);
    float4 a = p[0], b = p[1];
    bf16x8 o;
    o[0] = (bf16)a.x; o[1] = (bf16)a.y; o[2] = (bf16)a.z; o[3] = (bf16)a.w;
    o[4] = (bf16)b.x; o[5] = (bf16)b.y; o[6] = (bf16)b.z; o[7] = (bf16)b.w;
    *(bf16x8*)(Kc + bh * 262144 + rem) = o;
}

// past_v [4][8][1024][128] f32 -> Vt [4][8][128][2048] bf16 (transposed, first 1024 cols)
__global__ __launch_bounds__(256) void cvt_pastv_k(const float* __restrict__ in,
                                                   bf16* __restrict__ Vt) {
    const int tid = blockIdx.x * 256 + threadIdx.x;
    const int d   = tid & 127;
    const int kv4 = (tid >> 7) & 255;
    const int bh  = tid >> 15;
    u16x4v pk;
#pragma unroll
    for (int r = 0; r < 4; ++r) {
        float v = in[((long long)bh * 1024 + kv4 * 4 + r) * 128 + d];
        pk[r] = __builtin_bit_cast(unsigned short, (bf16)v);
    }
    *(u16x4v*)(Vt + ((long long)bh * 128 + d) * 2048 + kv4 * 4) = pk;
}

// ---------- GEMM: C[m][n] = sum_k A[m][k]*B[n][k] (+bias), m97-style 128x128 tile ----------
// MODE 0: bf16 row-major out, (acc+bias)*scale   (Q projection, scale folds 1/sqrt(D)*log2e)
// MODE 1: f32 row-major out, acc+bias            (final output projection)
// MODE 2: bf16 out scattered into K-cache [b][h][2048][128] at rows 1024+s
// MODE 3: bf16 out scattered transposed into Vt [b][h][128][2048] at cols 1024+s
template <int MODE>
__global__ __launch_bounds__(256) void gemm_bt(const bf16* __restrict__ A,
                                               const bf16* __restrict__ B,
                                               const float* __restrict__ bias,
                                               void* __restrict__ Cv,
                                               int M, int N, int K, float scale) {
    __shared__ bf16 Asm[128 * 32];
    __shared__ bf16 Bsm[128 * 32];
    const int t = threadIdx.x;
    const int lane = t & 63, w = t >> 6;
    const int quad = lane >> 4, l16 = lane & 15;
    const int wr = (w >> 1) * 64, wc = (w & 1) * 64;
    const long long m0 = (long long)blockIdx.y * 128, n0 = (long long)blockIdx.x * 128;

    f32x4 acc[4][4] = {};

    const int i1 = t, i2 = t + 256;
    const bf16* gA1 = A + (m0 + (i1 >> 2)) * K + (i1 & 3) * 8;
    const bf16* gA2 = A + (m0 + (i2 >> 2)) * K + (i2 & 3) * 8;
    const bf16* gB1 = B + (n0 + (i1 >> 2)) * K + (i1 & 3) * 8;
    const bf16* gB2 = B + (n0 + (i2 >> 2)) * K + (i2 & 3) * 8;
    bf16* lA1 = Asm + i1 * 8;
    bf16* lA2 = Asm + i2 * 8;
    bf16* lB1 = Bsm + i1 * 8;
    bf16* lB2 = Bsm + i2 * 8;

    for (int k0 = 0; k0 < K; k0 += 32) {
        glds16(gA1 + k0, lA1);
        glds16(gA2 + k0, lA2);
        glds16(gB1 + k0, lB1);
        glds16(gB2 + k0, lB2);
        __syncthreads();
        bf16x8 af[4], bfr[4];
#pragma unroll
        for (int i = 0; i < 4; ++i)
            af[i] = *(const bf16x8*)(Asm + (wr + i * 16 + l16) * 32 + quad * 8);
#pragma unroll
        for (int j = 0; j < 4; ++j)
            bfr[j] = *(const bf16x8*)(Bsm + (wc + j * 16 + l16) * 32 + quad * 8);
#pragma unroll
        for (int i = 0; i < 4; ++i)
#pragma unroll
            for (int j = 0; j < 4; ++j)
                acc[i][j] = MFMA16(af[i], bfr[j], acc[i][j]);
        __syncthreads();
    }

    float bs[4];
#pragma unroll
    for (int j = 0; j < 4; ++j) bs[j] = bias[n0 + wc + j * 16 + l16];

#pragma unroll
    for (int i = 0; i < 4; ++i) {
        const long long mbase = m0 + wr + i * 16 + quad * 4;
#pragma unroll
        for (int j = 0; j < 4; ++j) {
            const long long n = n0 + wc + j * 16 + l16;
            if (MODE == 0) {
                bf16* Cb = (bf16*)Cv;
#pragma unroll
                for (int r = 0; r < 4; ++r)
                    Cb[(mbase + r) * N + n] = (bf16)((acc[i][j][r] + bs[j]) * scale);
            } else if (MODE == 1) {
                float* Cf = (float*)Cv;
#pragma unroll
                for (int r = 0; r < 4; ++r)
                    Cf[(mbase + r) * N + n] = acc[i][j][r] + bs[j];
            } else if (MODE == 2) {
                bf16* Ck = (bf16*)Cv;
                const int h = (int)(n >> 7), d = (int)(n & 127);
#pragma unroll
                for (int r = 0; r < 4; ++r) {
                    const long long m = mbase + r;
                    const long long bb = m >> 10, s = m & 1023;
                    Ck[((bb * 8 + h) * 2048 + 1024 + s) * 128 + d] = (bf16)(acc[i][j][r] + bs[j]);
                }
            } else {
                bf16* Cvt = (bf16*)Cv;
                const int h = (int)(n >> 7), d = (int)(n & 127);
                const long long bb = mbase >> 10, s = mbase & 1023;
                u16x4v pk;
#pragma unroll
                for (int r = 0; r < 4; ++r)
                    pk[r] = __builtin_bit_cast(unsigned short, (bf16)(acc[i][j][r] + bs[j]));
                *(u16x4v*)(Cvt + ((bb * 8 + h) * 128 + d) * 2048 + 1024 + s) = pk;
            }
        }
    }
}

// ---------- flash attention ----------
// Q pre-scaled by log2e/sqrt(128); softmax in base 2.
// block = (qt, h, b); 4 waves x 32 q-rows = 128 q rows; kv tiles of 64 over 2048.
__global__ __launch_bounds__(256) void attn_k(const bf16* __restrict__ Qb,
                                              const bf16* __restrict__ Kc,
                                              const bf16* __restrict__ Vt,
                                              const int* __restrict__ amask,
                                              bf16* __restrict__ AO) {
    const int qt = blockIdx.x, h = blockIdx.y, b = blockIdx.z;
    const int hk = h >> 2;
    const int t = threadIdx.x, lane = t & 63, w = t >> 6;
    const int quad = lane >> 4, l16 = lane & 15;

    __shared__ bf16 Ksm[64][136];     // 272B rows: 16B aligned, odd*16 -> ~2-way conflicts
    __shared__ bf16 Vsm[128][72];     // Vt tile [d][kv], 144B rows
    __shared__ bf16 Psm[4][32][72];   // per-wave P round-trip

    bf16x8 qf[2][4];
    {
        const bf16* qb = Qb + (long long)(b * 1024 + qt * 128 + w * 32) * 4096 + h * 128;
#pragma unroll
        for (int rb = 0; rb < 2; ++rb)
#pragma unroll
            for (int s = 0; s < 4; ++s)
                qf[rb][s] = *(const bf16x8*)(qb + (long long)(rb * 16 + l16) * 4096 + s * 32 + quad * 8);
    }

    f32x4 O[2][8] = {};
    float mi[2][4], li[2][4];
#pragma unroll
    for (int rb = 0; rb < 2; ++rb)
#pragma unroll
        for (int r = 0; r < 4; ++r) { mi[rb][r] = -1e30f; li[rb][r] = 0.f; }

    const bf16* kg = Kc + (long long)(b * 8 + hk) * 2048 * 128;
    const bf16* vg = Vt + (long long)(b * 8 + hk) * 128 * 2048;
    const int* mrow = amask + b * 2048;

    for (int kv0 = 0; kv0 < 2048; kv0 += 64) {
        // stage K (64x128) and Vt (128x64)
#pragma unroll
        for (int c = 0; c < 4; ++c) {
            const int i = t + 256 * c;
            const int kr = i >> 4, kc = i & 15;
            *(bf16x8*)(&Ksm[kr][kc * 8]) = *(const bf16x8*)(kg + (long long)(kv0 + kr) * 128 + kc * 8);
            const int vr = i >> 3, vc = i & 7;
            *(bf16x8*)(&Vsm[vr][vc * 8]) = *(const bf16x8*)(vg + (long long)vr * 2048 + kv0 + vc * 8);
        }
        __syncthreads();

        bool ok[4];
#pragma unroll
        for (int ct = 0; ct < 4; ++ct) ok[ct] = (mrow[kv0 + ct * 16 + l16] == 0);

        // S = Q K^T  (C layout: col=l16 -> kv, row=quad*4+r -> q)
        f32x4 sacc[2][4] = {};
#pragma unroll
        for (int ct = 0; ct < 4; ++ct) {
#pragma unroll
            for (int s = 0; s < 4; ++s) {
                bf16x8 kf = *(const bf16x8*)(&Ksm[ct * 16 + l16][s * 32 + quad * 8]);
                sacc[0][ct] = MFMA16(qf[0][s], kf, sacc[0][ct]);
                sacc[1][ct] = MFMA16(qf[1][s], kf, sacc[1][ct]);
            }
        }

        // mask (log2-domain -1e9)
#pragma unroll
        for (int ct = 0; ct < 4; ++ct)
#pragma unroll
            for (int rb = 0; rb < 2; ++rb)
#pragma unroll
                for (int r = 0; r < 4; ++r)
                    sacc[rb][ct][r] = ok[ct] ? sacc[rb][ct][r] : -1.442695e9f;

        // online softmax (base 2)
        float alpha[2][4];
#pragma unroll
        for (int rb = 0; rb < 2; ++rb) {
#pragma unroll
            for (int r = 0; r < 4; ++r) {
                float mx = fmaxf(fmaxf(sacc[rb][0][r], sacc[rb][1][r]),
                                 fmaxf(sacc[rb][2][r], sacc[rb][3][r]));
                mx = rowmax16(mx);
                const float mnew = fmaxf(mi[rb][r], mx);
                const float al = exp2f(mi[rb][r] - mnew);
                float sum = 0.f;
#pragma unroll
                for (int ct = 0; ct < 4; ++ct) {
                    float p = exp2f(sacc[rb][ct][r] - mnew);
                    sacc[rb][ct][r] = p;
                    sum += p;
                }
                sum = rowsum16(sum);
                mi[rb][r] = mnew;
                li[rb][r] = li[rb][r] * al + sum;
                alpha[rb][r] = al;
            }
        }
        // rescale O, spill P to LDS (C layout -> A layout transform)
#pragma unroll
        for (int rb = 0; rb < 2; ++rb) {
#pragma unroll
            for (int dt = 0; dt < 8; ++dt)
#pragma unroll
                for (int r = 0; r < 4; ++r) O[rb][dt][r] *= alpha[rb][r];
#pragma unroll
            for (int ct = 0; ct < 4; ++ct)
#pragma unroll
                for (int r = 0; r < 4; ++r)
                    Psm[w][rb * 16 + quad * 4 + r][ct * 16 + l16] = (bf16)sacc[rb][ct][r];
        }

        // O += P V   (A = P from LDS, B = Vt tile)
#pragma unroll
        for (int s2 = 0; s2 < 2; ++s2) {
            bf16x8 pa0 = *(const bf16x8*)(&Psm[w][l16][s2 * 32 + quad * 8]);
            bf16x8 pa1 = *(const bf16x8*)(&Psm[w][16 + l16][s2 * 32 + quad * 8]);
#pragma unroll
            for (int dt = 0; dt < 8; ++dt) {
                bf16x8 vf = *(const bf16x8*)(&Vsm[dt * 16 + l16][s2 * 32 + quad * 8]);
                O[0][dt] = MFMA16(pa0, vf, O[0][dt]);
                O[1][dt] = MFMA16(pa1, vf, O[1][dt]);
            }
        }
        __syncthreads();
    }

    // epilogue: normalize and store bf16 [token][h*128+d]
#pragma unroll
    for (int rb = 0; rb < 2; ++rb) {
        float inv[4];
#pragma unroll
        for (int r = 0; r < 4; ++r) inv[r] = 1.0f / li[rb][r];
        const long long row0 = (long long)(b * 1024 + qt * 128 + w * 32 + rb * 16 + quad * 4);
#pragma unroll
        for (int dt = 0; dt < 8; ++dt)
#pragma unroll
            for (int r = 0; r < 4; ++r)
                AO[(row0 + r) * 4096 + h * 128 + dt * 16 + l16] = (bf16)(O[rb][dt][r] * inv[r]);
    }
}

// ---------- host launch ----------
extern "C" void kernel_launch(void* const* d_in, const int* in_sizes, int n_in,
                              void* d_out, int out_size, void* d_ws, size_t ws_size,
                              hipStream_t stream) {
    const float* hidden = (const float*)d_in[0];
    const float* past_k = (const float*)d_in[1];
    const float* past_v = (const float*)d_in[2];
    const int*   amask  = (const int*)d_in[3];
    const float* Wq = (const float*)d_in[4];
    const float* bq = (const float*)d_in[5];
    const float* Wk = (const float*)d_in[6];
    const float* bk = (const float*)d_in[7];
    const float* Wv = (const float*)d_in[8];
    const float* bv = (const float*)d_in[9];
    const float* Wo = (const float*)d_in[10];
    const float* bo = (const float*)d_in[11];

    // workspace layout (128 MB total)
    char* ws = (char*)d_ws;
    bf16* Xb  = (bf16*)(ws);                     // 32 MB  hidden bf16 [4096][4096]
    bf16* Wqb = (bf16*)(ws + (33ll << 20) * 1);  // offset 32MB: Wq bf16, later reused for Wo
    bf16* Kb  = (bf16*)(ws + (1ll << 26));       // 64MB:  K cache bf16 [4][8][2048][128]
    bf16* Vtb = (bf16*)(ws + (1ll << 26) + (1ll << 24)); // 80MB: V^T cache [4][8][128][2048]
    bf16* AOb = (bf16*)(ws + (3ll << 25));       // 96MB:  attention out bf16 [4096][4096]
    // scratch inside d_out (67MB, dead before final GEMM writes it)
    char* oc = (char*)d_out;
    bf16* Qb  = (bf16*)(oc);                     // 32 MB: scaled Q bf16 [4096][4096]
    bf16* Wkb = (bf16*)(oc + (1ll << 25));       // 8 MB
    bf16* Wvb = (bf16*)(oc + (1ll << 25) + (1ll << 23)); // 8 MB

    // fix Wqb offset: 32 MB exactly
    Wqb = (bf16*)(ws + (1ll << 25));

    const float qscale = 0.08838834764831845f * 1.44269504088896340f; // 1/sqrt(128) * log2(e)

    cvt_bf16_k<<<8192, 256, 0, stream>>>(hidden, Xb, 16777216ll);
    cvt_bf16_k<<<8192, 256, 0, stream>>>(Wq, Wqb, 16777216ll);
    cvt_bf16_k<<<2048, 256, 0, stream>>>(Wk, Wkb, 4194304ll);
    cvt_bf16_k<<<2048, 256, 0, stream>>>(Wv, Wvb, 4194304ll);
    cvt_pastk_k<<<2048, 256, 0, stream>>>(past_k, Kb);
    cvt_pastv_k<<<4096, 256, 0, stream>>>(past_v, Vtb);

    gemm_bt<0><<<dim3(32, 32), 256, 0, stream>>>(Xb, Wqb, bq, (void*)Qb, 4096, 4096, 4096, qscale);
    gemm_bt<2><<<dim3(8, 32), 256, 0, stream>>>(Xb, Wkb, bk, (void*)Kb, 4096, 1024, 4096, 1.0f);
    gemm_bt<3><<<dim3(8, 32), 256, 0, stream>>>(Xb, Wvb, bv, (void*)Vtb, 4096, 1024, 4096, 1.0f);

    // Wo -> bf16 (reuse Wqb buffer; stream-ordered after Q projection consumed it)
    cvt_bf16_k<<<8192, 256, 0, stream>>>(Wo, Wqb, 16777216ll);

    attn_k<<<dim3(8, 32, 4), 256, 0, stream>>>(Qb, Kb, Vtb, amask, AOb);

    gemm_bt<1><<<dim3(32, 32), 256, 0, stream>>>(AOb, Wqb, bo, d_out, 4096, 4096, 4096, 1.0f);
}